// Round 9
// baseline (253.185 us; speedup 1.0000x reference)
//
#include <hip/hip_runtime.h>
#include <math.h>

typedef float f32x4 __attribute__((ext_vector_type(4)));

#define NF 69u
#define TROWS 64u
#define TILE_FLOATS (TROWS * NF)     // 4416 = 64*69 -> tile-invariant (row,f) map
#define TILE_F4 (TILE_FLOATS / 4u)   // 1104
#define BLOCK 256u
#define NCH 5u                       // ceil(1104/256): 4 full + 1 masked (tid<80)

// ---------------------------------------------------------------------------
// Kernel 1: per-axis feature tables, padded to stride 8.
// tab8[c*8+ft] x-axis; tab8[8*W + c*8+ft] y-axis; ft: norm,sign,sin,cos,rtan
// ---------------------------------------------------------------------------
__global__ void pe_table_kernel(const int* __restrict__ hptr,
                                const int* __restrict__ wptr,
                                float* __restrict__ tab8) {
    const int H = *hptr;
    const int W = *wptr;
    const int total = W + H;
    for (int i = (int)(blockIdx.x * blockDim.x + threadIdx.x); i < total;
         i += (int)(gridDim.x * blockDim.x)) {
        const bool is_y = (i >= W);
        const int c = is_y ? (i - W) : i;
        const int size = is_y ? H : W;
        double norm = 0.0, angle = 0.0;
        if (size > 1) {
            const double r = (double)c / (double)(size - 1);
            norm = 2.0 * r - 1.0;
            angle = M_PI * r;
        }
        const double d = (double)c - 0.5 * (double)size;
        const float sgn = (d > 0.0) ? 1.0f : ((d < 0.0) ? -1.0f : 0.0f);
        const int base = (is_y ? 8 * W : 0) + 8 * c;
        tab8[base + 0] = (float)norm;
        tab8[base + 1] = sgn;
        tab8[base + 2] = (float)sin(angle);
        tab8[base + 3] = (float)cos(angle);
        tab8[base + 4] = (float)rint(tan(angle));
    }
}

__device__ __forceinline__ void pe_coords(unsigned int q, unsigned int W,
                                          unsigned int H, bool pot,
                                          unsigned int lw,
                                          unsigned int& w, unsigned int& h) {
    if (pot) {                 // uniform branch; bench path: 2 VALU ops
        w = q & (W - 1u);
        h = (q >> lw) & (H - 1u);
    } else {
        const unsigned int t = q / W;
        w = q - t * W;
        h = t % H;
    }
}

// One output element: fm in [0,69), qq = combined row index, (wq,hq) coords.
__device__ __forceinline__ float pe_elem(unsigned int fm, unsigned int qq,
                                         unsigned int wq, unsigned int hq,
                                         const float* __restrict__ x,
                                         const float* __restrict__ tab8,
                                         unsigned int yoff8) {
    // Branchless one-hot covers fm >= 11 (73% of elements).
    float val = ((fm >= 11u && fm < 40u && wq == fm - 11u) ||
                 (fm >= 40u && hq == fm - 40u)) ? 1.0f : 0.0f;
    if (fm <= 10u) {           // exec-masked region: x + 10 header feats
        if (fm == 0u) {
            val = x[qq];
        } else {
            const unsigned int g = fm - 1u;
            val = (g & 1u) ? tab8[yoff8 + 8u * hq + (g >> 1)]
                           : tab8[8u * wq + (g >> 1)];
        }
    }
    return val;
}

// ---------------------------------------------------------------------------
// Kernel 2: direct-to-global, fill-shaped. No LDS, no barriers. Per-thread
// tile-invariant (row,f0) pattern precomputed once; per tile only pow2
// coord math + branchless selects + plain dwordx4 stores.
// ---------------------------------------------------------------------------
__global__ __launch_bounds__(BLOCK) void pe_main_kernel(
    const float* __restrict__ x,
    const int* __restrict__ hptr, const int* __restrict__ wptr,
    const float* __restrict__ tab8,
    float* __restrict__ out, unsigned int Q /* = B*H*W rows */) {
    const unsigned int W = (unsigned int)*wptr;
    const unsigned int H = (unsigned int)*hptr;
    const unsigned int yoff8 = 8u * W;
    const bool pot = ((W & (W - 1u)) == 0u) && ((H & (H - 1u)) == 0u);
    const unsigned int lw = pot ? (unsigned int)(31 - __clz((int)W)) : 0u;
    const unsigned int tid = threadIdx.x;
    const unsigned int ntiles = (Q + TROWS - 1u) / TROWS;
    const size_t total = (size_t)Q * NF;

    // Tile-invariant pattern: packed (row<<8)|f0 per chunk (static-indexed
    // array in unrolled loop -> registers; div by literal 69 = magic-mul).
    unsigned int pat[NCH];
#pragma unroll
    for (unsigned int j = 0u; j < NCH; ++j) {
        const unsigned int local = tid + BLOCK * j;
        const unsigned int ff = 4u * local;
        pat[j] = ((ff / 69u) << 8) | (ff % 69u);
    }

    for (unsigned int T = blockIdx.x; T < ntiles; T += gridDim.x) {
        const size_t basef = (size_t)T * TILE_FLOATS;
        const unsigned int Trow = T * TROWS;
        const bool full = basef + TILE_FLOATS <= total;  // uniform per block
#pragma unroll
        for (unsigned int j = 0u; j < NCH; ++j) {
            const unsigned int local = tid + BLOCK * j;
            if (j == NCH - 1u && local >= TILE_F4) continue;  // tid>=80 mask
            const unsigned int row = pat[j] >> 8;
            const unsigned int f0 = pat[j] & 0xFFu;
            const unsigned int q = Trow + row;
            unsigned int w0, h0, w1, h1;
            pe_coords(q, W, H, pot, lw, w0, h0);
            pe_coords(q + 1u, W, H, pot, lw, w1, h1);  // arith only; safe
            f32x4 v;
#pragma unroll
            for (unsigned int e = 0u; e < 4u; ++e) {
                const unsigned int ff = f0 + e;
                const bool wr = ff >= NF;          // element wraps to row+1
                const unsigned int fm = wr ? ff - NF : ff;
                const unsigned int qq = wr ? q + 1u : q;
                const unsigned int wq = wr ? w1 : w0;
                const unsigned int hq = wr ? h1 : h0;
                v[e] = (full || basef + 4u * local + e < total)
                           ? pe_elem(fm, qq, wq, hq, x, tab8, yoff8)
                           : 0.0f;
            }
            if (full) {
                *(f32x4*)(out + basef + 4u * local) = v;   // plain store
            } else {
                // tail tile: per-element guarded scalar stores
#pragma unroll
                for (unsigned int e = 0u; e < 4u; ++e) {
                    const size_t idx = basef + 4u * local + e;
                    if (idx < total) out[idx] = v[e];
                }
            }
        }
    }
}

extern "C" void kernel_launch(void* const* d_in, const int* in_sizes, int n_in,
                              void* d_out, int out_size, void* d_ws, size_t ws_size,
                              hipStream_t stream) {
    const float* x = (const float*)d_in[0];
    const int* hptr = (const int*)d_in[1];
    const int* wptr = (const int*)d_in[2];
    float* out = (float*)d_out;
    float* tab8 = (float*)d_ws;  // (W+H)*8*4 B = 32 KB for the bench shape

    pe_table_kernel<<<8, 256, 0, stream>>>(hptr, wptr, tab8);

    const unsigned int Q = (unsigned int)in_sizes[0];  // B*H*W rows
    const unsigned int ntiles = (Q + TROWS - 1u) / TROWS;
    unsigned int blocks = ntiles < 2048u ? ntiles : 2048u;
    if (blocks == 0u) blocks = 1u;
    pe_main_kernel<<<blocks, BLOCK, 0, stream>>>(x, hptr, wptr, tab8, out, Q);
}

// Round 10
// 118.993 us; speedup vs baseline: 2.1277x; 2.1277x over previous
//
#include <hip/hip_runtime.h>
#include <math.h>

typedef float f32x4 __attribute__((ext_vector_type(4)));

#define NF 69u                         // floats per output row (1 + 68)
#define TROWS 64u                      // rows per block-tile (lane = row)
#define TILE_FLOATS (TROWS * NF)       // 4416
#define TILE_F4 (TILE_FLOATS / 4u)     // 1104
#define BLOCK 256u

// ---------------------------------------------------------------------------
// Kernel 1: per-axis feature tables, padded to stride 8.
// tab8[c*8+ft] x-axis; tab8[8*W + c*8+ft] y-axis; ft: norm,sign,sin,cos,rtan
// ---------------------------------------------------------------------------
__global__ void pe_table_kernel(const int* __restrict__ hptr,
                                const int* __restrict__ wptr,
                                float* __restrict__ tab8) {
    const int H = *hptr;
    const int W = *wptr;
    const int total = W + H;
    for (int i = (int)(blockIdx.x * blockDim.x + threadIdx.x); i < total;
         i += (int)(gridDim.x * blockDim.x)) {
        const bool is_y = (i >= W);
        const int c = is_y ? (i - W) : i;
        const int size = is_y ? H : W;
        double norm = 0.0, angle = 0.0;
        if (size > 1) {
            const double r = (double)c / (double)(size - 1);
            norm = 2.0 * r - 1.0;
            angle = M_PI * r;
        }
        const double d = (double)c - 0.5 * (double)size;
        const float sgn = (d > 0.0) ? 1.0f : ((d < 0.0) ? -1.0f : 0.0f);
        const int base = (is_y ? 8 * W : 0) + 8 * c;
        tab8[base + 0] = (float)norm;
        tab8[base + 1] = sgn;
        tab8[base + 2] = (float)sin(angle);
        tab8[base + 3] = (float)cos(angle);
        tab8[base + 4] = (float)rint(tan(angle));
    }
}

// Per-tile register state. Only wave 0 carries load results (headers).
struct Regs {
    unsigned int w, h;
    bool valid;
    f32x4 xa, ya;
    float xa4, ya4, xv;
};

// Issue all global loads for tile T. Called BEFORE the store phase so the
// loads are the OLDEST entries in the vmcnt queue (in-order retirement ->
// later waits never need to drain the NT stores issued after them).
__device__ __forceinline__ void pe_load(
    Regs& r, unsigned int T, unsigned int Q, unsigned int W, unsigned int H,
    bool pot, unsigned int lw, unsigned int yoff8,
    unsigned int lane, unsigned int wv,
    const float* __restrict__ x, const float* __restrict__ tab8) {
    const unsigned int q = T * TROWS + lane;
    r.valid = q < Q;
    if (pot) {                     // bench path: 2 VALU ops, no divides
        r.w = q & (W - 1u);
        r.h = (q >> lw) & (H - 1u);
    } else {
        const unsigned int t = q / W;
        r.w = q - t * W;
        r.h = t % H;
    }
    if (wv == 0u && r.valid) {     // only wave 0 needs header values
        r.xa  = *(const f32x4*)(tab8 + 8u * r.w);
        r.xa4 = tab8[8u * r.w + 4u];
        r.ya  = *(const f32x4*)(tab8 + yoff8 + 8u * r.h);
        r.ya4 = tab8[yoff8 + 8u * r.h + 4u];
        r.xv  = x[q];
    }
}

// Pure LDS writes from registers: ZERO global ops. Contiguous slot ranges
// per wave; one-hot slots are compare+select against compile-time constants.
__device__ __forceinline__ void pe_compute(float* __restrict__ buf,
                                           const Regs& r,
                                           unsigned int lane,
                                           unsigned int wv) {
    if (!r.valid) return;
    float* row = buf + lane * NF;   // stride 69: (5 mod 32) -> 2-way, free
    if (wv == 0u) {                 // f 0..16: x, 10 header feats, one-hot 0..5
        row[0] = r.xv;
        row[1] = r.xa[0]; row[2]  = r.ya[0];
        row[3] = r.xa[1]; row[4]  = r.ya[1];
        row[5] = r.xa[2]; row[6]  = r.ya[2];
        row[7] = r.xa[3]; row[8]  = r.ya[3];
        row[9] = r.xa4;   row[10] = r.ya4;
#pragma unroll
        for (unsigned int f = 11u; f < 17u; ++f)
            row[f] = (r.w == f - 11u) ? 1.0f : 0.0f;
    } else if (wv == 1u) {          // f 17..33: one-hot x 6..22
#pragma unroll
        for (unsigned int f = 17u; f < 34u; ++f)
            row[f] = (r.w == f - 11u) ? 1.0f : 0.0f;
    } else if (wv == 2u) {          // f 34..50: one-hot x 23..28, y 0..10
#pragma unroll
        for (unsigned int f = 34u; f < 40u; ++f)
            row[f] = (r.w == f - 11u) ? 1.0f : 0.0f;
#pragma unroll
        for (unsigned int f = 40u; f < 51u; ++f)
            row[f] = (r.h == f - 40u) ? 1.0f : 0.0f;
    } else {                        // f 51..68: one-hot y 11..28
#pragma unroll
        for (unsigned int f = 51u; f < 69u; ++f)
            row[f] = (r.h == f - 40u) ? 1.0f : 0.0f;
    }
}

// ---------------------------------------------------------------------------
// Kernel 2: double-buffered pipeline, one lgkm-only barrier per tile.
// Loop: prefetch regs(T+g) -> barrier -> store tile T (static-count NT
// stores) -> compute(T+g) from registers. NT stores are never drained.
// ---------------------------------------------------------------------------
__global__ __launch_bounds__(BLOCK) void pe_main_kernel(
    const float* __restrict__ x,
    const int* __restrict__ hptr, const int* __restrict__ wptr,
    const float* __restrict__ tab8,
    float* __restrict__ out, unsigned int Q /* = B*H*W rows */) {
    __shared__ __align__(16) float lds[2][TILE_FLOATS];  // 35328 B

    const unsigned int W = (unsigned int)*wptr;
    const unsigned int H = (unsigned int)*hptr;
    const unsigned int yoff8 = 8u * W;
    const bool pot = ((W & (W - 1u)) == 0u) && ((H & (H - 1u)) == 0u);
    const unsigned int lw = pot ? (unsigned int)(31 - __clz((int)W)) : 0u;
    const unsigned int lane = threadIdx.x & 63u;
    const unsigned int wv = threadIdx.x >> 6;
    const unsigned int ntiles = (Q + TROWS - 1u) / TROWS;
    const unsigned int g = gridDim.x;

    unsigned int T = blockIdx.x;
    if (T >= ntiles) return;  // uniform per block

    Regs rr;
    pe_load(rr, T, Q, W, H, pot, lw, yoff8, lane, wv, x, tab8);
    pe_compute(lds[0], rr, lane, wv);
    unsigned int cur = 0u;

    for (; T < ntiles; T += g) {
        const unsigned int Tn = T + g;

        // ---- prefetch tile T+g regs BEFORE the stores (oldest in vmcnt) ----
        Regs rn;
        if (Tn < ntiles)
            pe_load(rn, Tn, Q, W, H, pot, lw, yoff8, lane, wv, x, tab8);

        // LDS-only barrier: global NT stores stay in flight across it.
        asm volatile("s_waitcnt lgkmcnt(0)\n\ts_barrier" ::: "memory");

        // ---- store tile T: static-count read/store pairs ----
        const unsigned int rem = Q - T * TROWS;
        const size_t obase = (size_t)T * (size_t)TILE_FLOATS;
        const f32x4* lp = (const f32x4*)(cur ? lds[1] : lds[0]);
        f32x4* op = (f32x4*)(out + obase);   // 4416*T floats: 16B-aligned

        if (rem >= TROWS) {
            const unsigned int t0 = threadIdx.x;
            f32x4 v0 = lp[t0];
            __builtin_nontemporal_store(v0, op + t0);
            f32x4 v1 = lp[t0 + 256u];
            __builtin_nontemporal_store(v1, op + t0 + 256u);
            f32x4 v2 = lp[t0 + 512u];
            __builtin_nontemporal_store(v2, op + t0 + 512u);
            f32x4 v3 = lp[t0 + 768u];
            __builtin_nontemporal_store(v3, op + t0 + 768u);
            if (t0 < TILE_F4 - 1024u) {      // last 80 float4s
                f32x4 v4 = lp[t0 + 1024u];
                __builtin_nontemporal_store(v4, op + t0 + 1024u);
            }
        } else {
            // partial tail tile (not hit for the bench shape)
            const unsigned int nfl = rem * NF;
            const unsigned int n4 = nfl >> 2;
            const float* lf = (const float*)lp;
            for (unsigned int j = threadIdx.x; j < n4; j += BLOCK)
                __builtin_nontemporal_store(lp[j], op + j);
            for (unsigned int j = (n4 << 2) + threadIdx.x; j < nfl; j += BLOCK)
                __builtin_nontemporal_store(lf[j], out + obase + j);
        }

        // ---- compute tile T+g into the other buffer: registers only ----
        if (Tn < ntiles)
            pe_compute(cur ? lds[0] : lds[1], rn, lane, wv);
        cur ^= 1u;
    }
}

extern "C" void kernel_launch(void* const* d_in, const int* in_sizes, int n_in,
                              void* d_out, int out_size, void* d_ws, size_t ws_size,
                              hipStream_t stream) {
    const float* x = (const float*)d_in[0];
    const int* hptr = (const int*)d_in[1];
    const int* wptr = (const int*)d_in[2];
    float* out = (float*)d_out;
    float* tab8 = (float*)d_ws;  // (W+H)*8*4 B = 32 KB for the bench shape

    pe_table_kernel<<<8, 256, 0, stream>>>(hptr, wptr, tab8);

    const unsigned int Q = (unsigned int)in_sizes[0];  // B*H*W rows
    const unsigned int ntiles = (Q + TROWS - 1u) / TROWS;
    unsigned int blocks = ntiles < 2048u ? ntiles : 2048u;
    if (blocks == 0u) blocks = 1u;
    pe_main_kernel<<<blocks, BLOCK, 0, stream>>>(x, hptr, wptr, tab8, out, Q);
}